// Round 2
// baseline (241.092 us; speedup 1.0000x reference)
//
#include <hip/hip_runtime.h>
#include <hip/hip_bf16.h>

// ConvIntrinsic: gather+barycentric -> patch-operator -> 8 rotated folds.
// Circular-correlation FFT formulation (R8, verified): 8-pt real DFT over
// the angular index on both sides; ĉ[k]=X*[k]Y[k] per bin k={0&4,1,2,3};
// inverse DFT + bias + relu + k-pair fold give the 8 rotation outputs.
//
// R11: gemm REVERTED to the verified R9 structure (70 us; R10's register-
// direct A regressed 2x: 16-row x 2560B-stride scatter = 16x 64B segments
// per instr + 8-of-16 L2 channel aliasing, and vmcnt(0) barrier drain
// killed the intended pipelining). prep_fft REWORKED: it was ~60-68 us
// (~4x its 16 us HBM floor), stall-bound on the dependent bary->mesh
// gather chain at 2.9 waves/SIMD. Now: bary slice staged to LDS once per
// block (coalesced), gathers issue independently; one point per 64-lane
// wave (f = 64 x float2) -> 6000 waves (5.9/SIMD) for latency hiding.

#define N_PTS 6000
#define RR 5
#define AA 8
#define FF 128
#define OO 128
#define QQ 40            // R*A
#define KD2 1280         // per-bin GEMM K: 5 rho x 2 part x 128 f
#define SIG_BLOCKS 1500  // 4 points per block (1 point per wave)
#define W2_BLOCKS 128    // 2 j per block
#define CCQ 0.70710678118654752f
#define RT2 1.41421356237309515f

#define AHS ((size_t)N_PTS * KD2)  // per-bin Ahat elems
#define BHS ((size_t)512 * KD2)    // per-bin Bhat elems

typedef __bf16 bf16_t;
typedef __bf16 bf16x2 __attribute__((ext_vector_type(2)));
typedef __bf16 bf16x8 __attribute__((ext_vector_type(8)));
typedef float f32x4 __attribute__((ext_vector_type(4)));

#define GLOAD_LDS16(g, l)                                              \
  __builtin_amdgcn_global_load_lds(                                    \
      (const __attribute__((address_space(1))) void*)(g),              \
      (__attribute__((address_space(3))) void*)(l), 16, 0, 0)

// 8-point real DFT, X[k] = sum_a x[a] e^{-2pi i k a/8} (verified R8).
#define DFT8V(xx, c, X0, X4, Xr1, Xi1, Xr2, Xi2, Xr3, Xi3)             \
  {                                                                    \
    const float s0_ = xx[0][c] + xx[4][c], s1_ = xx[1][c] + xx[5][c];  \
    const float s2_ = xx[2][c] + xx[6][c], s3_ = xx[3][c] + xx[7][c];  \
    const float d0_ = xx[0][c] - xx[4][c], d1_ = xx[1][c] - xx[5][c];  \
    const float d2_ = xx[2][c] - xx[6][c], d3_ = xx[3][c] - xx[7][c];  \
    const float e_ = CCQ * (d1_ - d3_), o_ = CCQ * (d1_ + d3_);        \
    X0 = (s0_ + s2_) + (s1_ + s3_);                                    \
    X4 = (s0_ + s2_) - (s1_ + s3_);                                    \
    Xr2 = s0_ - s2_; Xi2 = s3_ - s1_;                                  \
    Xr1 = d0_ + e_;  Xi1 = -(o_ + d2_);                                \
    Xr3 = d0_ - e_;  Xi3 = d2_ - o_;                                   \
  }

#define PACK2(dst, X)                                                  \
  {                                                                    \
    bf16x2 pv_;                                                        \
    pv_[0] = (bf16_t)X[0]; pv_[1] = (bf16_t)X[1];                      \
    *(bf16x2*)(dst) = pv_;                                             \
  }

// ------------------------------------------------------- FFT prep pass
// blocks [0,1500): 4 points each, ONE POINT PER WAVE (64 lanes = 128 f
//   as float2). bary slice (960 floats) staged to LDS coalesced; per-a
//   (idx,w) records are broadcast LDS reads -> all mesh-row gathers
//   independent and deep in flight. DFT8 in regs -> bf16x2 stores.
// blocks [1500,1628): Bhat (rot=0 cols) -> DFT -> 4 bins (x 1/8 norm).
__global__ __launch_bounds__(256, 6) void prep_fft_kernel(
    const float* __restrict__ mesh, const float* __restrict__ bary,
    const float* __restrict__ kw, const float* __restrict__ interp,
    bf16_t* __restrict__ Ahat, bf16_t* __restrict__ Bhat) {
  __shared__ float sh[RR * AA * QQ];  // 1600 floats; sig uses first 960
  const int bx = blockIdx.x;
  const int tid = threadIdx.x;

  if (bx < SIG_BLOCKS) {
    const int wave = tid >> 6;  // 0..3 -> point
    const int l = tid & 63;     // f = l*2
    const int n = bx * 4 + wave;
    // stage 4 points' bary (4 x 240 floats, contiguous) into LDS
    const float* bbase = bary + (size_t)bx * 4 * (QQ * 6);
    for (int i = tid; i < 960; i += 256) sh[i] = bbase[i];
    __syncthreads();
    const float* bp = sh + wave * 240;
    bf16_t* an = Ahat + (size_t)n * KD2 + l * 2;
#pragma unroll
    for (int rho = 0; rho < RR; ++rho) {
      float x[8][2];
#pragma unroll
      for (int a = 0; a < 8; ++a) {
        const float* rec = bp + (rho * 8 + a) * 6;  // wave-uniform (LDS)
        const float2 p0 = *(const float2*)(rec);
        const float2 p1 = *(const float2*)(rec + 2);
        const float2 p2 = *(const float2*)(rec + 4);
        const float2 v0 =
            *(const float2*)(mesh + (size_t)((int)p0.x) * FF + l * 2);
        const float2 v1 =
            *(const float2*)(mesh + (size_t)((int)p1.x) * FF + l * 2);
        const float2 v2 =
            *(const float2*)(mesh + (size_t)((int)p2.x) * FF + l * 2);
        x[a][0] = p0.y * v0.x + p1.y * v1.x + p2.y * v2.x;
        x[a][1] = p0.y * v0.y + p1.y * v1.y + p2.y * v2.y;
      }
      float X0[2], X4[2], Xr1[2], Xi1[2], Xr2[2], Xi2[2], Xr3[2], Xi3[2];
#pragma unroll
      for (int c = 0; c < 2; ++c)
        DFT8V(x, c, X0[c], X4[c], Xr1[c], Xi1[c], Xr2[c], Xi2[c], Xr3[c],
              Xi3[c]);
      bf16_t* dst = an + rho * 256;
      PACK2(dst, X0);                  PACK2(dst + 128, X4);
      PACK2(dst + AHS, Xr1);           PACK2(dst + AHS + 128, Xi1);
      PACK2(dst + 2 * AHS, Xr2);       PACK2(dst + 2 * AHS + 128, Xi2);
      PACK2(dst + 3 * AHS, Xr3);       PACK2(dst + 3 * AHS + 128, Xi3);
    }
  } else {
    // ---- B side: two j columns per block (128 threads each).
    const int j = (bx - SIG_BLOCKS) * 2 + (tid >> 7);  // 0..255
    const int f = tid & 127;
    for (int i = tid; i < RR * AA * QQ; i += 256) sh[i] = interp[i];
    __syncthreads();
    const int o = (j >> 1) & 127;
    const int k = j & 1;
    float acc[QQ];
#pragma unroll
    for (int q = 0; q < QQ; ++q) acc[q] = 0.f;
    for (int r = 0; r < RR; ++r) {
      for (int a = 0; a < AA; ++a) {
        const float kv =
            kw[((size_t)((r * AA + a) * 2 + k) * OO + o) * FF + f];
        const float4* ip = (const float4*)(sh + (r * AA + a) * QQ);
#pragma unroll
        for (int q4 = 0; q4 < QQ / 4; ++q4) {
          const float4 w4 = ip[q4];
          acc[q4 * 4 + 0] += w4.x * kv;
          acc[q4 * 4 + 1] += w4.y * kv;
          acc[q4 * 4 + 2] += w4.z * kv;
          acc[q4 * 4 + 3] += w4.w * kv;
        }
      }
    }
    // DFT over a; 1/8 normalization folded in. Col j = Re-type, 256+j =
    // Im-type (bin0 packs Z0/Z4 there; bins 1-3 pack [Yr|Yi]/[Yi|-Yr]).
    const float SC = 0.125f;
    bf16_t* b1p = Bhat + (size_t)j * KD2 + f;
    bf16_t* b2p = Bhat + (size_t)(256 + j) * KD2 + f;
#pragma unroll
    for (int rho = 0; rho < RR; ++rho) {
      float xx[8][1];
#pragma unroll
      for (int a = 0; a < 8; ++a) xx[a][0] = acc[rho * 8 + a];
      float Y0, Y4, Yr1, Yi1, Yr2, Yi2, Yr3, Yi3;
      DFT8V(xx, 0, Y0, Y4, Yr1, Yi1, Yr2, Yi2, Yr3, Yi3);
      const int off = rho * 256;
      b1p[off] = (bf16_t)(Y0 * SC);        b1p[off + 128] = (bf16_t)0.f;
      b2p[off] = (bf16_t)0.f;              b2p[off + 128] = (bf16_t)(Y4 * SC);
      b1p[BHS + off] = (bf16_t)(Yr1 * SC);
      b1p[BHS + off + 128] = (bf16_t)(Yi1 * SC);
      b2p[BHS + off] = (bf16_t)(Yi1 * SC);
      b2p[BHS + off + 128] = (bf16_t)(-Yr1 * SC);
      b1p[2 * BHS + off] = (bf16_t)(Yr2 * SC);
      b1p[2 * BHS + off + 128] = (bf16_t)(Yi2 * SC);
      b2p[2 * BHS + off] = (bf16_t)(Yi2 * SC);
      b2p[2 * BHS + off + 128] = (bf16_t)(-Yr2 * SC);
      b1p[3 * BHS + off] = (bf16_t)(Yr3 * SC);
      b1p[3 * BHS + off + 128] = (bf16_t)(Yi3 * SC);
      b2p[3 * BHS + off] = (bf16_t)(Yi3 * SC);
      b2p[3 * BHS + off + 128] = (bf16_t)(-Yr3 * SC);
    }
  }
}

// --------------------------------------- fused GEMM + iDFT + epilogue
// (verified R9 structure, 70 us) Grid 768: xcd=L&7, t=L>>3; slab
// g=xcd+8*(t>>4) (0..47), j-tile jt=t&15. Block = 128m x 16j; B tile =
// 32 cols (rows 0-15: cols j0+., Re Z; rows 16-31: cols 256+j0+., Im Z)
// -> same lane holds Re/Im of the same j. Bins loop sequentially (K=80
// BK-iters total); after each bin's K-loop, fold cf*Re+sf*Im into an
// 8-rot accumulator (iDFT coeffs, verified R8). Then bias+relu+shfl
// k-fold epilogue (verified R1-R8).
__global__ __launch_bounds__(256, 3) void gemm_fused_fft_kernel(
    const bf16_t* __restrict__ Ahat, const bf16_t* __restrict__ Bhat,
    const float* __restrict__ bias, float* __restrict__ out) {
  const int L = blockIdx.x;
  const int xcd = L & 7;
  const int t = L >> 3;                // 0..95
  const int g = xcd + 8 * (t >> 4);    // 0..47
  const int jt = t & 15;
  const int m0 = g * 128;
  if (m0 >= N_PTS) return;
  const int j0 = jt * 16;

  __shared__ bf16_t As[128 * 64];
  __shared__ bf16_t Bs[32 * 64];
  const int tid = threadIdx.x;
  const int wave = tid >> 6;
  const int lane = tid & 63;
  const int quad = lane >> 4;
  const int tl = lane & 15;
  const int wm = wave * 32;
  const int srow = lane >> 3;
  const int sc = (lane & 7) ^ srow;

  // this wave's B staging chunk (8 rows of the 32-row B tile)
  const int crow = wave * 8;
  const int colbase = (crow < 16) ? (j0 + crow) : (256 + j0 + (crow - 16));
  const int gcol = colbase + srow;

  // iDFT coefficients: c_rot = sum_b cf[b][rot]*ReZ_b + sf[b][rot]*ImZ_b
  // (bin0: ReZ=Z0 cf=1, ImZ=Z4 sf=(-1)^rot). Verified in R8.
  static const float CF[4][8] = {
      {1, 1, 1, 1, 1, 1, 1, 1},
      {2, RT2, 0, -RT2, -2, -RT2, 0, RT2},
      {2, 0, -2, 0, 2, 0, -2, 0},
      {2, -RT2, 0, RT2, -2, RT2, 0, -RT2}};
  static const float SF[4][8] = {
      {1, -1, 1, -1, 1, -1, 1, -1},
      {0, -RT2, -2, -RT2, 0, RT2, 2, RT2},
      {0, -2, 0, 2, 0, -2, 0, 2},
      {0, -RT2, 2, -RT2, 0, RT2, -2, RT2}};

  f32x4 oacc[8][2];
#pragma unroll
  for (int rot = 0; rot < 8; ++rot)
#pragma unroll
    for (int mm = 0; mm < 2; ++mm) oacc[rot][mm] = {0.f, 0.f, 0.f, 0.f};

#pragma unroll
  for (int b = 0; b < 4; ++b) {
    const bf16_t* A = Ahat + (size_t)b * AHS;
    const bf16_t* B = Bhat + (size_t)b * BHS;
    f32x4 z[2][2];
#pragma unroll
    for (int mm = 0; mm < 2; ++mm)
#pragma unroll
      for (int cc = 0; cc < 2; ++cc) z[mm][cc] = {0.f, 0.f, 0.f, 0.f};

    for (int kk = 0; kk < KD2; kk += 64) {
      __syncthreads();
#pragma unroll
      for (int i = 0; i < 4; ++i) {
        const int row = wave * 32 + i * 8;
        int gm = m0 + row + srow;
        gm = gm < N_PTS ? gm : (N_PTS - 1);
        GLOAD_LDS16(A + (size_t)gm * KD2 + kk + sc * 8, As + row * 64);
      }
      GLOAD_LDS16(B + (size_t)gcol * KD2 + kk + sc * 8, Bs + crow * 64);
      __syncthreads();
#pragma unroll
      for (int ks = 0; ks < 2; ++ks) {
        const int ch = (((ks * 4 + quad) ^ (tl & 7)) * 8);
        bf16x8 af[2], bfr[2];
        af[0] = *(const bf16x8*)(As + (wm + tl) * 64 + ch);
        af[1] = *(const bf16x8*)(As + (wm + 16 + tl) * 64 + ch);
        bfr[0] = *(const bf16x8*)(Bs + tl * 64 + ch);
        bfr[1] = *(const bf16x8*)(Bs + (16 + tl) * 64 + ch);
#pragma unroll
        for (int mm = 0; mm < 2; ++mm)
#pragma unroll
          for (int cc = 0; cc < 2; ++cc)
            z[mm][cc] = __builtin_amdgcn_mfma_f32_16x16x32_bf16(
                af[mm], bfr[cc], z[mm][cc], 0, 0, 0);
      }
    }
    // fold this bin into the 8-rot accumulator
#pragma unroll
    for (int rot = 0; rot < 8; ++rot) {
      const float cf = CF[b][rot], sf = SF[b][rot];
#pragma unroll
      for (int mm = 0; mm < 2; ++mm)
#pragma unroll
        for (int r = 0; r < 4; ++r)
          oacc[rot][mm][r] += cf * z[mm][0][r] + sf * z[mm][1][r];
    }
  }

  // epilogue: v=relu(oacc+40*bias[k,o]); lanes (tl, tl^1)=(k0,k1) of same o
  const int j = j0 + tl;  // 0..255
  const float bb = 40.0f * bias[((j & 1) << 7) | (j >> 1)];
  const int o = j >> 1;
#pragma unroll
  for (int rot = 0; rot < 8; ++rot)
#pragma unroll
    for (int mm = 0; mm < 2; ++mm)
#pragma unroll
      for (int r = 0; r < 4; ++r) {
        const int mrow = m0 + wm + mm * 16 + quad * 4 + r;
        float v = oacc[rot][mm][r] + bb;
        v = v > 0.f ? v : 0.f;
        const float vs = v + __shfl_xor(v, 1, 64);
        if (((lane & 1) == 0) && (mrow < N_PTS))
          out[(size_t)mrow * 1024 + rot * 128 + o] = vs;
      }
}

extern "C" void kernel_launch(void* const* d_in, const int* in_sizes, int n_in,
                              void* d_out, int out_size, void* d_ws,
                              size_t ws_size, hipStream_t stream) {
  const float* mesh = (const float*)d_in[0];    // (6000,128)
  const float* bary = (const float*)d_in[1];    // (6000,5,8,3,2)
  const float* kw = (const float*)d_in[2];      // (5,8,2,128,128)
  const float* bias = (const float*)d_in[3];    // (2,128)
  const float* interp = (const float*)d_in[4];  // (5,8,40)
  float* out = (float*)d_out;                   // (6000,8,128)

  bf16_t* Ahat = (bf16_t*)d_ws;                          // 61.44 MB
  bf16_t* Bhat = (bf16_t*)((char*)d_ws + 4 * AHS * 2);   // +5.24 MB

  prep_fft_kernel<<<SIG_BLOCKS + W2_BLOCKS, 256, 0, stream>>>(
      mesh, bary, kw, interp, Ahat, Bhat);
  gemm_fused_fft_kernel<<<768, 256, 0, stream>>>(Ahat, Bhat, bias, out);
}

// Round 3
// 165.600 us; speedup vs baseline: 1.4559x; 1.4559x over previous
//
#include <hip/hip_runtime.h>
#include <hip/hip_bf16.h>

// ConvIntrinsic: gather+barycentric -> patch-operator -> 8 rotated folds.
// Circular-correlation FFT formulation (R8, verified): 8-pt real DFT over
// the angular index on both sides; ĉ[k]=X*[k]Y[k] per bin k={0&4,1,2,3};
// inverse DFT + bias + relu + k-pair fold give the 8 rotation outputs.
//
// R12: prep traffic fix. R11 counters: prep FETCH 194 + WRITE 230 MB vs
// ~88 MB ideal (5x), 3.9 TB/s, occupancy 54% -> traffic-bound, not
// latency-bound. Amplification tracks access width (R11 halved widths vs
// R9 and got ~1.7x more time/traffic; gemm's 16 B/lane loads show no
// inflation). Fix: K-RE-LAYOUT k = rho*256 + f*2 + part (dot-product
// index permutation, applied to BOTH Ahat and Bhat -> gemm unchanged,
// byte-identical to the verified 70 us R9 kernel). Sig lanes pack
// (Re,Im) pairs -> every store is bf16x8 = 16 B/lane; gathers back to
// float4 = 16 B/lane; bary staged via LDS (R11's good idea kept).

#define N_PTS 6000
#define RR 5
#define AA 8
#define FF 128
#define OO 128
#define QQ 40            // R*A
#define KD2 1280         // per-bin GEMM K: 5 rho x 2 part x 128 f
#define SIG_BLOCKS 750   // 8 points per block
#define W2_BLOCKS 128    // 2 j per block
#define CCQ 0.70710678118654752f
#define RT2 1.41421356237309515f

#define AHS ((size_t)N_PTS * KD2)  // per-bin Ahat elems
#define BHS ((size_t)512 * KD2)    // per-bin Bhat elems

typedef __bf16 bf16_t;
typedef __bf16 bf16x2 __attribute__((ext_vector_type(2)));
typedef __bf16 bf16x8 __attribute__((ext_vector_type(8)));
typedef float f32x4 __attribute__((ext_vector_type(4)));

#define GLOAD_LDS16(g, l)                                              \
  __builtin_amdgcn_global_load_lds(                                    \
      (const __attribute__((address_space(1))) void*)(g),              \
      (__attribute__((address_space(3))) void*)(l), 16, 0, 0)

// 8-point real DFT, X[k] = sum_a x[a] e^{-2pi i k a/8} (verified R8).
#define DFT8V(xx, c, X0, X4, Xr1, Xi1, Xr2, Xi2, Xr3, Xi3)             \
  {                                                                    \
    const float s0_ = xx[0][c] + xx[4][c], s1_ = xx[1][c] + xx[5][c];  \
    const float s2_ = xx[2][c] + xx[6][c], s3_ = xx[3][c] + xx[7][c];  \
    const float d0_ = xx[0][c] - xx[4][c], d1_ = xx[1][c] - xx[5][c];  \
    const float d2_ = xx[2][c] - xx[6][c], d3_ = xx[3][c] - xx[7][c];  \
    const float e_ = CCQ * (d1_ - d3_), o_ = CCQ * (d1_ + d3_);        \
    X0 = (s0_ + s2_) + (s1_ + s3_);                                    \
    X4 = (s0_ + s2_) - (s1_ + s3_);                                    \
    Xr2 = s0_ - s2_; Xi2 = s3_ - s1_;                                  \
    Xr1 = d0_ + e_;  Xi1 = -(o_ + d2_);                                \
    Xr3 = d0_ - e_;  Xi3 = d2_ - o_;                                   \
  }

// pack 4 (P,Q) part-pairs interleaved: [P0,Q0,P1,Q1,P2,Q2,P3,Q3] (16 B)
#define PACKP(dst, P, Q)                                               \
  {                                                                    \
    bf16x8 pv_;                                                        \
    pv_[0] = (bf16_t)P[0]; pv_[1] = (bf16_t)Q[0];                      \
    pv_[2] = (bf16_t)P[1]; pv_[3] = (bf16_t)Q[1];                      \
    pv_[4] = (bf16_t)P[2]; pv_[5] = (bf16_t)Q[2];                      \
    pv_[6] = (bf16_t)P[3]; pv_[7] = (bf16_t)Q[3];                      \
    *(bf16x8*)(dst) = pv_;                                             \
  }

// ------------------------------------------------------- FFT prep pass
// blocks [0,750): 8 points each; 256 thr = 8 point-slots x 32 f4-lanes.
//   bary slice (1920 floats) staged to LDS coalesced; gathers float4
//   (16 B/lane), DFT8 in regs, 4 x bf16x8 (16 B/lane) interleaved-pair
//   stores per (point,rho) into the 4 bins.
// blocks [750,878): Bhat (rot=0 cols) -> DFT -> 4 bins (x 1/8 norm),
//   bf16x2 part-pair stores matching the interleaved K layout.
__global__ __launch_bounds__(256, 6) void prep_fft_kernel(
    const float* __restrict__ mesh, const float* __restrict__ bary,
    const float* __restrict__ kw, const float* __restrict__ interp,
    bf16_t* __restrict__ Ahat, bf16_t* __restrict__ Bhat) {
  __shared__ float sh[1920];  // sig: 8x240 bary; w2: 1600 interp
  const int bx = blockIdx.x;
  const int tid = threadIdx.x;

  if (bx < SIG_BLOCKS) {
    const int slot = tid >> 5;  // 0..7
    const int l = tid & 31;     // f = l*4
    const int n = bx * 8 + slot;
    const float* bbase = bary + (size_t)bx * 8 * (QQ * 6);
    for (int i = tid; i < 1920; i += 256) sh[i] = bbase[i];
    __syncthreads();
    const float* bp = sh + slot * 240;
    bf16_t* an = Ahat + (size_t)n * KD2 + l * 8;
#pragma unroll
    for (int rho = 0; rho < RR; ++rho) {
      float x[8][4];
#pragma unroll
      for (int a = 0; a < 8; ++a) {
        const float* rec = bp + (rho * 8 + a) * 6;  // slot-uniform (LDS)
        const float2 p0 = *(const float2*)(rec);
        const float2 p1 = *(const float2*)(rec + 2);
        const float2 p2 = *(const float2*)(rec + 4);
        const float4 v0 =
            *(const float4*)(mesh + (size_t)((int)p0.x) * FF + l * 4);
        const float4 v1 =
            *(const float4*)(mesh + (size_t)((int)p1.x) * FF + l * 4);
        const float4 v2 =
            *(const float4*)(mesh + (size_t)((int)p2.x) * FF + l * 4);
        x[a][0] = p0.y * v0.x + p1.y * v1.x + p2.y * v2.x;
        x[a][1] = p0.y * v0.y + p1.y * v1.y + p2.y * v2.y;
        x[a][2] = p0.y * v0.z + p1.y * v1.z + p2.y * v2.z;
        x[a][3] = p0.y * v0.w + p1.y * v1.w + p2.y * v2.w;
      }
      float X0[4], X4[4], Xr1[4], Xi1[4], Xr2[4], Xi2[4], Xr3[4], Xi3[4];
#pragma unroll
      for (int c = 0; c < 4; ++c)
        DFT8V(x, c, X0[c], X4[c], Xr1[c], Xi1[c], Xr2[c], Xi2[c], Xr3[c],
              Xi3[c]);
      // interleaved K layout: k = rho*256 + f*2 + part
      bf16_t* dst = an + rho * 256;
      PACKP(dst, X0, X4);              // bin0: part0=Z0-src, part1=Z4-src
      PACKP(dst + AHS, Xr1, Xi1);      // bins 1-3: (Re, Im)
      PACKP(dst + 2 * AHS, Xr2, Xi2);
      PACKP(dst + 3 * AHS, Xr3, Xi3);
    }
  } else {
    // ---- B side: two j columns per block (128 threads each).
    const int j = (bx - SIG_BLOCKS) * 2 + (tid >> 7);  // 0..255
    const int f = tid & 127;
    for (int i = tid; i < RR * AA * QQ; i += 256) sh[i] = interp[i];
    __syncthreads();
    const int o = (j >> 1) & 127;
    const int k = j & 1;
    float acc[QQ];
#pragma unroll
    for (int q = 0; q < QQ; ++q) acc[q] = 0.f;
    for (int r = 0; r < RR; ++r) {
      for (int a = 0; a < AA; ++a) {
        const float kv =
            kw[((size_t)((r * AA + a) * 2 + k) * OO + o) * FF + f];
        const float4* ip = (const float4*)(sh + (r * AA + a) * QQ);
#pragma unroll
        for (int q4 = 0; q4 < QQ / 4; ++q4) {
          const float4 w4 = ip[q4];
          acc[q4 * 4 + 0] += w4.x * kv;
          acc[q4 * 4 + 1] += w4.y * kv;
          acc[q4 * 4 + 2] += w4.z * kv;
          acc[q4 * 4 + 3] += w4.w * kv;
        }
      }
    }
    // DFT over a; 1/8 normalization folded in. Interleaved K layout:
    // col j (Re-type) gets parts (p0,p1) per f; col 256+j (Im-type)
    // gets the conjugate-rotated pair. bin0: (Y0,0) / (0,Y4).
    const float SC = 0.125f;
    bf16_t* b1p = Bhat + (size_t)j * KD2;
    bf16_t* b2p = Bhat + (size_t)(256 + j) * KD2;
#pragma unroll
    for (int rho = 0; rho < RR; ++rho) {
      float xx[8][1];
#pragma unroll
      for (int a = 0; a < 8; ++a) xx[a][0] = acc[rho * 8 + a];
      float Y0, Y4, Yr1, Yi1, Yr2, Yi2, Yr3, Yi3;
      DFT8V(xx, 0, Y0, Y4, Yr1, Yi1, Yr2, Yi2, Yr3, Yi3);
      const int off = rho * 256 + f * 2;
      bf16x2 w;
      w[0] = (bf16_t)(Y0 * SC);   w[1] = (bf16_t)0.f;
      *(bf16x2*)(b1p + off) = w;
      w[0] = (bf16_t)0.f;         w[1] = (bf16_t)(Y4 * SC);
      *(bf16x2*)(b2p + off) = w;
      w[0] = (bf16_t)(Yr1 * SC);  w[1] = (bf16_t)(Yi1 * SC);
      *(bf16x2*)(b1p + BHS + off) = w;
      w[0] = (bf16_t)(Yi1 * SC);  w[1] = (bf16_t)(-Yr1 * SC);
      *(bf16x2*)(b2p + BHS + off) = w;
      w[0] = (bf16_t)(Yr2 * SC);  w[1] = (bf16_t)(Yi2 * SC);
      *(bf16x2*)(b1p + 2 * BHS + off) = w;
      w[0] = (bf16_t)(Yi2 * SC);  w[1] = (bf16_t)(-Yr2 * SC);
      *(bf16x2*)(b2p + 2 * BHS + off) = w;
      w[0] = (bf16_t)(Yr3 * SC);  w[1] = (bf16_t)(Yi3 * SC);
      *(bf16x2*)(b1p + 3 * BHS + off) = w;
      w[0] = (bf16_t)(Yi3 * SC);  w[1] = (bf16_t)(-Yr3 * SC);
      *(bf16x2*)(b2p + 3 * BHS + off) = w;
    }
  }
}

// --------------------------------------- fused GEMM + iDFT + epilogue
// (verified R9 structure, 70 us — UNCHANGED; K-permutation is applied
// identically to both operands so this kernel is layout-agnostic.)
// Grid 768: xcd=L&7, t=L>>3; slab g=xcd+8*(t>>4) (0..47), j-tile jt=t&15.
// Block = 128m x 16j; B tile = 32 cols (rows 0-15: cols j0+., Re Z; rows
// 16-31: cols 256+j0+., Im Z) -> same lane holds Re/Im of the same j.
// Bins loop sequentially (K=80 BK iters total); after each bin's K-loop,
// fold cf*Re+sf*Im into an 8-rot accumulator (iDFT coeffs, verified R8).
// Then bias+relu+shfl k-fold epilogue (verified R1-R8).
__global__ __launch_bounds__(256, 3) void gemm_fused_fft_kernel(
    const bf16_t* __restrict__ Ahat, const bf16_t* __restrict__ Bhat,
    const float* __restrict__ bias, float* __restrict__ out) {
  const int L = blockIdx.x;
  const int xcd = L & 7;
  const int t = L >> 3;                // 0..95
  const int g = xcd + 8 * (t >> 4);    // 0..47
  const int jt = t & 15;
  const int m0 = g * 128;
  if (m0 >= N_PTS) return;
  const int j0 = jt * 16;

  __shared__ bf16_t As[128 * 64];
  __shared__ bf16_t Bs[32 * 64];
  const int tid = threadIdx.x;
  const int wave = tid >> 6;
  const int lane = tid & 63;
  const int quad = lane >> 4;
  const int tl = lane & 15;
  const int wm = wave * 32;
  const int srow = lane >> 3;
  const int sc = (lane & 7) ^ srow;

  // this wave's B staging chunk (8 rows of the 32-row B tile)
  const int crow = wave * 8;
  const int colbase = (crow < 16) ? (j0 + crow) : (256 + j0 + (crow - 16));
  const int gcol = colbase + srow;

  // iDFT coefficients: c_rot = sum_b cf[b][rot]*ReZ_b + sf[b][rot]*ImZ_b
  // (bin0: ReZ=Z0 cf=1, ImZ=Z4 sf=(-1)^rot). Verified in R8.
  static const float CF[4][8] = {
      {1, 1, 1, 1, 1, 1, 1, 1},
      {2, RT2, 0, -RT2, -2, -RT2, 0, RT2},
      {2, 0, -2, 0, 2, 0, -2, 0},
      {2, -RT2, 0, RT2, -2, RT2, 0, -RT2}};
  static const float SF[4][8] = {
      {1, -1, 1, -1, 1, -1, 1, -1},
      {0, -RT2, -2, -RT2, 0, RT2, 2, RT2},
      {0, -2, 0, 2, 0, -2, 0, 2},
      {0, -RT2, 2, -RT2, 0, RT2, -2, RT2}};

  f32x4 oacc[8][2];
#pragma unroll
  for (int rot = 0; rot < 8; ++rot)
#pragma unroll
    for (int mm = 0; mm < 2; ++mm) oacc[rot][mm] = {0.f, 0.f, 0.f, 0.f};

#pragma unroll
  for (int b = 0; b < 4; ++b) {
    const bf16_t* A = Ahat + (size_t)b * AHS;
    const bf16_t* B = Bhat + (size_t)b * BHS;
    f32x4 z[2][2];
#pragma unroll
    for (int mm = 0; mm < 2; ++mm)
#pragma unroll
      for (int cc = 0; cc < 2; ++cc) z[mm][cc] = {0.f, 0.f, 0.f, 0.f};

    for (int kk = 0; kk < KD2; kk += 64) {
      __syncthreads();
#pragma unroll
      for (int i = 0; i < 4; ++i) {
        const int row = wave * 32 + i * 8;
        int gm = m0 + row + srow;
        gm = gm < N_PTS ? gm : (N_PTS - 1);
        GLOAD_LDS16(A + (size_t)gm * KD2 + kk + sc * 8, As + row * 64);
      }
      GLOAD_LDS16(B + (size_t)gcol * KD2 + kk + sc * 8, Bs + crow * 64);
      __syncthreads();
#pragma unroll
      for (int ks = 0; ks < 2; ++ks) {
        const int ch = (((ks * 4 + quad) ^ (tl & 7)) * 8);
        bf16x8 af[2], bfr[2];
        af[0] = *(const bf16x8*)(As + (wm + tl) * 64 + ch);
        af[1] = *(const bf16x8*)(As + (wm + 16 + tl) * 64 + ch);
        bfr[0] = *(const bf16x8*)(Bs + tl * 64 + ch);
        bfr[1] = *(const bf16x8*)(Bs + (16 + tl) * 64 + ch);
#pragma unroll
        for (int mm = 0; mm < 2; ++mm)
#pragma unroll
          for (int cc = 0; cc < 2; ++cc)
            z[mm][cc] = __builtin_amdgcn_mfma_f32_16x16x32_bf16(
                af[mm], bfr[cc], z[mm][cc], 0, 0, 0);
      }
    }
    // fold this bin into the 8-rot accumulator
#pragma unroll
    for (int rot = 0; rot < 8; ++rot) {
      const float cf = CF[b][rot], sf = SF[b][rot];
#pragma unroll
      for (int mm = 0; mm < 2; ++mm)
#pragma unroll
        for (int r = 0; r < 4; ++r)
          oacc[rot][mm][r] += cf * z[mm][0][r] + sf * z[mm][1][r];
    }
  }

  // epilogue: v=relu(oacc+40*bias[k,o]); lanes (tl, tl^1)=(k0,k1) of same o
  const int j = j0 + tl;  // 0..255
  const float bb = 40.0f * bias[((j & 1) << 7) | (j >> 1)];
  const int o = j >> 1;
#pragma unroll
  for (int rot = 0; rot < 8; ++rot)
#pragma unroll
    for (int mm = 0; mm < 2; ++mm)
#pragma unroll
      for (int r = 0; r < 4; ++r) {
        const int mrow = m0 + wm + mm * 16 + quad * 4 + r;
        float v = oacc[rot][mm][r] + bb;
        v = v > 0.f ? v : 0.f;
        const float vs = v + __shfl_xor(v, 1, 64);
        if (((lane & 1) == 0) && (mrow < N_PTS))
          out[(size_t)mrow * 1024 + rot * 128 + o] = vs;
      }
}

extern "C" void kernel_launch(void* const* d_in, const int* in_sizes, int n_in,
                              void* d_out, int out_size, void* d_ws,
                              size_t ws_size, hipStream_t stream) {
  const float* mesh = (const float*)d_in[0];    // (6000,128)
  const float* bary = (const float*)d_in[1];    // (6000,5,8,3,2)
  const float* kw = (const float*)d_in[2];      // (5,8,2,128,128)
  const float* bias = (const float*)d_in[3];    // (2,128)
  const float* interp = (const float*)d_in[4];  // (5,8,40)
  float* out = (float*)d_out;                   // (6000,8,128)

  bf16_t* Ahat = (bf16_t*)d_ws;                          // 61.44 MB
  bf16_t* Bhat = (bf16_t*)((char*)d_ws + 4 * AHS * 2);   // +5.24 MB

  prep_fft_kernel<<<SIG_BLOCKS + W2_BLOCKS, 256, 0, stream>>>(
      mesh, bary, kw, interp, Ahat, Bhat);
  gemm_fused_fft_kernel<<<768, 256, 0, stream>>>(Ahat, Bhat, bias, out);
}